// Round 4
// baseline (288.384 us; speedup 1.0000x reference)
//
#include <hip/hip_runtime.h>
#include <hip/hip_bf16.h>

// AttentionBlock: B=16, N=2048, D=128, fp32 in/out.
// R4: no-max softmax (scores provably small), l via MFMA-with-ones,
//     q_pad folded into V at projection, barrier-free attention k-loop
//     (K/V fragments direct from L1/L2), lean proj without W-LDS.

#define NEGBIG -4294967296.0f            // float32(-2^32+1) rounds to -2^32
#define SCALE  0.08838834764831845f      // 1/sqrt(128)

typedef __bf16 bf16x8 __attribute__((ext_vector_type(8)));
typedef float  f32x4  __attribute__((ext_vector_type(4)));

// ---------------- Kernel 1: projections + masks ----------------
// 1024 blocks x 128 thr; block owns 32 rows; wave w owns rows base+w*16+col.
static __device__ __forceinline__ void do_gemm(
    const float* __restrict__ W, const float* __restrict__ bias,
    const bf16x8 a[4], __bf16* __restrict__ dst, __bf16* stage,
    const float qpadr[4], bool tp,
    int tid, int wave, int col, int quad, int rowbase)
{
    f32x4 acc[8];
    #pragma unroll
    for (int ct = 0; ct < 8; ++ct) { f32x4 z = {0.f, 0.f, 0.f, 0.f}; acc[ct] = z; }
    #pragma unroll
    for (int f = 0; f < 4; ++f) {
        #pragma unroll
        for (int ct = 0; ct < 8; ++ct) {
            const float* wp = W + (size_t)(ct * 16 + col) * 128 + f * 32 + quad * 8;
            float4 w0 = *(const float4*)wp, w1 = *(const float4*)(wp + 4);
            bf16x8 bfr = {(__bf16)w0.x, (__bf16)w0.y, (__bf16)w0.z, (__bf16)w0.w,
                          (__bf16)w1.x, (__bf16)w1.y, (__bf16)w1.z, (__bf16)w1.w};
            acc[ct] = __builtin_amdgcn_mfma_f32_16x16x32_bf16(a[f], bfr, acc[ct], 0, 0, 0);
        }
    }
    // C-layout: out-row = quad*4+r, out-d = ct*16+col
    #pragma unroll
    for (int ct = 0; ct < 8; ++ct) {
        float bv = bias[ct * 16 + col];
        #pragma unroll
        for (int r = 0; r < 4; ++r) {
            float v = (acc[ct][r] + bv) * qpadr[r];
            if (tp) stage[(ct * 16 + col) * 40 + wave * 16 + quad * 4 + r] = (__bf16)v;  // [d][m]
            else    stage[(wave * 16 + quad * 4 + r) * 136 + ct * 16 + col] = (__bf16)v; // [row][d]
        }
    }
    __syncthreads();
    if (!tp) {
        // 32 rows x 256 B: 4 threads/row x 64 B
        int r = tid >> 2, seg = (tid & 3) * 32;
        uint4* g4 = (uint4*)(dst + (size_t)(rowbase + r) * 128 + seg);
        const uint4* s4 = (const uint4*)&stage[r * 136 + seg];
        g4[0] = s4[0]; g4[1] = s4[1]; g4[2] = s4[2]; g4[3] = s4[3];
    } else {
        // evT [b][d][2048], this block owns a 32-wide m-slice: 128 d-rows x 64 B
        int d = tid;
        int bb = rowbase >> 11, mb = rowbase & 2047;
        uint4* g4 = (uint4*)(dst + (size_t)bb * 128 * 2048 + (size_t)d * 2048 + mb);
        const uint4* s4 = (const uint4*)&stage[d * 40];
        g4[0] = s4[0]; g4[1] = s4[1]; g4[2] = s4[2]; g4[3] = s4[3];
    }
    __syncthreads();
}

__global__ __launch_bounds__(128, 2) void proj_kernel(
    const float* __restrict__ Q, const float* __restrict__ K,
    const int* __restrict__ PM,
    const float* __restrict__ Wq, const float* __restrict__ Bq,
    const float* __restrict__ Wk, const float* __restrict__ Bk,
    const float* __restrict__ Wv, const float* __restrict__ Bv,
    __bf16* __restrict__ eqb, __bf16* __restrict__ ekb, __bf16* __restrict__ evT,
    float2* __restrict__ mscale)
{
    __shared__ __bf16 stage[128 * 40];   // 10 KB (also covers 32*136 = 4352)
    const int tid  = threadIdx.x;
    const int wave = tid >> 6, lane = tid & 63;
    const int col  = lane & 15, quad = lane >> 4;
    const int rowbase = blockIdx.x * 32;
    const int myrow   = rowbase + wave * 16 + col;

    // A-frags (fp32 -> bf16) + exact fp32 row sums for masks
    bf16x8 aq[4], ak[4];
    float qs = 0.f, kss = 0.f;
    #pragma unroll
    for (int f = 0; f < 4; ++f) {
        const float* pq = Q + (size_t)myrow * 128 + f * 32 + quad * 8;
        const float* pk = K + (size_t)myrow * 128 + f * 32 + quad * 8;
        float4 q0 = *(const float4*)pq, q1 = *(const float4*)(pq + 4);
        float4 k0 = *(const float4*)pk, k1 = *(const float4*)(pk + 4);
        float qv[8] = {q0.x, q0.y, q0.z, q0.w, q1.x, q1.y, q1.z, q1.w};
        float kv[8] = {k0.x, k0.y, k0.z, k0.w, k1.x, k1.y, k1.z, k1.w};
        #pragma unroll
        for (int j = 0; j < 8; ++j) {
            qs += qv[j]; kss += kv[j];
            aq[f][j] = (__bf16)qv[j];
            ak[f][j] = (__bf16)kv[j];
        }
    }
    // full-row sums live in all lanes after xor-16/32
    qs  += __shfl_xor(qs, 16);  qs  += __shfl_xor(qs, 32);
    kss += __shfl_xor(kss, 16); kss += __shfl_xor(kss, 32);
    float qpadv = (qs != 0.f) ? 1.f : 0.f;   // lane holds value for row wave*16+col
    if (quad == 0) {
        int pmv = PM[myrow];
        float2 msc;
        msc.x = (pmv != 0) ? SCALE : 0.f;
        msc.y = (pmv != 0) ? 0.f : ((kss == 0.f) ? NEGBIG : 0.f);
        mscale[myrow] = msc;
    }

    const float one4[4] = {1.f, 1.f, 1.f, 1.f};
    // q_pad for C-rows quad*4+r: fetch from the lane holding that row's sum
    float qpr[4];
    #pragma unroll
    for (int r = 0; r < 4; ++r) qpr[r] = __shfl(qpadv, quad * 4 + r);

    do_gemm(Wq, Bq, aq, eqb, stage, one4, false, tid, wave, col, quad, rowbase);
    do_gemm(Wk, Bk, ak, ekb, stage, one4, false, tid, wave, col, quad, rowbase);
    do_gemm(Wv, Bv, ak, evT, stage, qpr,  true,  tid, wave, col, quad, rowbase);
}

// ---------------- Kernel 2: barrier-free flash attention ----------------
// 512 blocks x 128 thr (2 waves); wave owns 32 q-rows (qs=2). No __syncthreads
// in the k-loop: K/V fragments read direct from global (L1/L2-hot), only the
// wave-private P strip round-trips LDS. No running max (scores bounded);
// l accumulated via MFMA with a ones B-operand.
__global__ __launch_bounds__(128, 2) void attn_kernel(
    const __bf16* __restrict__ eqb, const __bf16* __restrict__ ekb,
    const __bf16* __restrict__ evT, const float2* __restrict__ mscale,
    const float* __restrict__ Q, float* __restrict__ out)
{
    __shared__ __bf16 pt[2][32 * 72];    // per-wave P strip [q][m], 9.2 KB total

    const int tid  = threadIdx.x;
    const int wave = tid >> 6, lane = tid & 63;
    const int col  = lane & 15, quad = lane >> 4;
    // swizzle: co-resident blocks (i, i+256) share b; XCD (i%8) sees 2 batches
    const int b  = ((blockIdx.x >> 1) & 7) | ((blockIdx.x & 1) << 3);
    const int qt = (blockIdx.x >> 4) & 31;
    const int rowg0 = b * 2048 + qt * 64 + wave * 32;
    const size_t bV = (size_t)b * 128 * 2048;

    bf16x8 aqf[2][4];
    #pragma unroll
    for (int q2 = 0; q2 < 2; ++q2)
        #pragma unroll
        for (int f = 0; f < 4; ++f)
            aqf[q2][f] = *(const bf16x8*)&eqb[(size_t)(rowg0 + q2 * 16 + col) * 128 + f * 32 + quad * 8];

    bf16x8 ones;
    #pragma unroll
    for (int j = 0; j < 8; ++j) ones[j] = (__bf16)1.0f;

    f32x4 o[2][8], lac[2];
    #pragma unroll
    for (int q2 = 0; q2 < 2; ++q2) {
        #pragma unroll
        for (int dt = 0; dt < 8; ++dt) { f32x4 z = {0.f, 0.f, 0.f, 0.f}; o[q2][dt] = z; }
        f32x4 z = {0.f, 0.f, 0.f, 0.f}; lac[q2] = z;
    }

    for (int it = 0; it < 32; ++it) {
        const int mbase = it * 64;
        // S = eq @ ek^T : B-frags straight from ekb (row m, d-contiguous)
        f32x4 s[2][4];
        #pragma unroll
        for (int q2 = 0; q2 < 2; ++q2)
            #pragma unroll
            for (int mt = 0; mt < 4; ++mt) { f32x4 z = {0.f, 0.f, 0.f, 0.f}; s[q2][mt] = z; }
        #pragma unroll
        for (int f = 0; f < 4; ++f) {
            bf16x8 bk[4];
            #pragma unroll
            for (int mt = 0; mt < 4; ++mt)
                bk[mt] = *(const bf16x8*)&ekb[(size_t)(b * 2048 + mbase + mt * 16 + col) * 128 + f * 32 + quad * 8];
            #pragma unroll
            for (int mt = 0; mt < 4; ++mt) {
                s[0][mt] = __builtin_amdgcn_mfma_f32_16x16x32_bf16(aqf[0][f], bk[mt], s[0][mt], 0, 0, 0);
                s[1][mt] = __builtin_amdgcn_mfma_f32_16x16x32_bf16(aqf[1][f], bk[mt], s[1][mt], 0, 0, 0);
            }
        }
        // e = exp(s*msel + movr); store raw e to P strip (A-operand order)
        #pragma unroll
        for (int mt = 0; mt < 4; ++mt) {
            float2 ms = mscale[b * 2048 + mbase + mt * 16 + col];
            #pragma unroll
            for (int q2 = 0; q2 < 2; ++q2)
                #pragma unroll
                for (int r = 0; r < 4; ++r) {
                    float e = __expf(s[q2][mt][r] * ms.x + ms.y);
                    pt[wave][(q2 * 16 + quad * 4 + r) * 72 + mt * 16 + col] = (__bf16)e;
                }
        }
        // O += P @ evq ; l += P @ 1   (evq already has q_pad folded in)
        #pragma unroll
        for (int k2 = 0; k2 < 2; ++k2) {
            bf16x8 pa0 = *(const bf16x8*)&pt[wave][(col) * 72 + k2 * 32 + quad * 8];
            bf16x8 pa1 = *(const bf16x8*)&pt[wave][(16 + col) * 72 + k2 * 32 + quad * 8];
            #pragma unroll
            for (int dt = 0; dt < 8; ++dt) {
                bf16x8 bv = *(const bf16x8*)&evT[bV + (size_t)(dt * 16 + col) * 2048 + mbase + k2 * 32 + quad * 8];
                o[0][dt] = __builtin_amdgcn_mfma_f32_16x16x32_bf16(pa0, bv, o[0][dt], 0, 0, 0);
                o[1][dt] = __builtin_amdgcn_mfma_f32_16x16x32_bf16(pa1, bv, o[1][dt], 0, 0, 0);
            }
            lac[0] = __builtin_amdgcn_mfma_f32_16x16x32_bf16(pa0, ones, lac[0], 0, 0, 0);
            lac[1] = __builtin_amdgcn_mfma_f32_16x16x32_bf16(pa1, ones, lac[1], 0, 0, 0);
        }
    }

    // epilogue: normalize, add residual queries, store fp32
    #pragma unroll
    for (int q2 = 0; q2 < 2; ++q2) {
        float inv[4];
        #pragma unroll
        for (int r = 0; r < 4; ++r) inv[r] = 1.f / lac[q2][r];
        #pragma unroll
        for (int dt = 0; dt < 8; ++dt)
            #pragma unroll
            for (int r = 0; r < 4; ++r) {
                size_t idx = (size_t)(rowg0 + q2 * 16 + quad * 4 + r) * 128 + dt * 16 + col;
                out[idx] = o[q2][dt][r] * inv[r] + Q[idx];
            }
    }
}

extern "C" void kernel_launch(void* const* d_in, const int* in_sizes, int n_in,
                              void* d_out, int out_size, void* d_ws, size_t ws_size,
                              hipStream_t stream)
{
    const float* Q  = (const float*)d_in[0];
    const float* K  = (const float*)d_in[1];
    const int*   PM = (const int*)d_in[2];
    const float* Wq = (const float*)d_in[3];
    const float* Bq = (const float*)d_in[4];
    const float* Wk = (const float*)d_in[5];
    const float* Bk = (const float*)d_in[6];
    const float* Wv = (const float*)d_in[7];
    const float* Bv = (const float*)d_in[8];
    float* out = (float*)d_out;

    const size_t SZE = (size_t)16 * 2048 * 128;     // 4,194,304 elements
    __bf16* eqb = (__bf16*)d_ws;                    // 8 MB
    __bf16* ekb = eqb + SZE;                        // 8 MB
    __bf16* evT = ekb + SZE;                        // 8 MB, layout [B][D][N], q_pad folded
    float2* mscale = (float2*)(evT + SZE);          // 256 KB: {sel*SCALE, ovr}

    proj_kernel<<<1024, 128, 0, stream>>>(Q, K, PM, Wq, Bq, Wk, Bk, Wv, Bv,
                                          eqb, ekb, evT, mscale);
    attn_kernel<<<512, 128, 0, stream>>>(eqb, ekb, evT, mscale, Q, out);
}